// Round 3
// baseline (835.974 us; speedup 1.0000x reference)
//
#include <hip/hip_runtime.h>
#include <hip/hip_bf16.h>
#include <math.h>

#define CIN   512
#define COUT  512
#define NB    16
#define WD    512
#define HIN   32
#define HUP   66
#define RES   64
#define LRELU 0.2f
#define ACT_GAIN 1.4142135623730951f

typedef __attribute__((ext_vector_type(8))) short short8;
typedef __attribute__((ext_vector_type(8))) unsigned short ushort8;
typedef __attribute__((ext_vector_type(4))) float float4v;

// ---------------- styles = w @ A^T / sqrt(512) + bias ----------------
__global__ void styles2_kernel(const float* __restrict__ w,
                               const float* __restrict__ aw,
                               const float* __restrict__ ab,
                               float* __restrict__ styles) {
    int b = blockIdx.x;          // 16
    int cig = blockIdx.y;        // 8
    int lane = threadIdx.x & 63, wv = threadIdx.x >> 6;
    __shared__ float wsh[WD];
    for (int e = threadIdx.x; e < WD; e += 256) wsh[e] = w[b * WD + e];
    __syncthreads();
    for (int r = 0; r < 16; ++r) {
        int ci = cig * 64 + wv * 16 + r;
        const float* arow = aw + (size_t)ci * WD;
        float acc = 0.f;
        for (int k = lane; k < WD; k += 64) acc += arow[k] * wsh[k];
        for (int off = 32; off; off >>= 1) acc += __shfl_down(acc, off, 64);
        if (lane == 0)
            styles[b * CIN + ci] = acc * 0.04419417382415922f + ab[ci];
    }
}

// ---- weights: wsq fp32 + pre-flipped bf16 pack wb[cc][t][ci_hi][cout][ci_lo] ----
__global__ void prep_weights(const float* __restrict__ weight,
                             float* __restrict__ wsq,
                             __hip_bfloat16* __restrict__ wb) {
    int idx = blockIdx.x * 256 + threadIdx.x;   // 262144
    int ci = idx & (CIN - 1);                   // lanes -> consecutive ci: coalesced 36B rows
    int co = idx >> 9;
    const float* wp = weight + ((size_t)co * CIN + ci) * 9;
    int cc = ci >> 5, chi = (ci >> 3) & 3, clo = ci & 7;
    float s = 0.f;
#pragma unroll
    for (int t = 0; t < 9; ++t) {
        float v = wp[t];
        s += v * v;
        int tf = 8 - t;   // flipped tap
        wb[((((size_t)cc * 9 + tf) * 4 + chi) * COUT + co) * 8 + clo] = __float2bfloat16(v);
    }
    wsq[(size_t)co * CIN + ci] = s;
}

// ---------------- dcoef[b,co] = rsqrt( sum_ci wsq[co,ci]*styles^2 + 1e-8 ) ----------------
__global__ void dcoef2_kernel(const float* __restrict__ styles,
                              const float* __restrict__ wsq,
                              float* __restrict__ dcoef) {
    int b = blockIdx.x;          // 16
    int cog = blockIdx.y;        // 8
    int lane = threadIdx.x & 63, wv = threadIdx.x >> 6;
    __shared__ float s2[CIN];
    for (int e = threadIdx.x; e < CIN; e += 256) {
        float s = styles[b * CIN + e];
        s2[e] = s * s;
    }
    __syncthreads();
    for (int r = 0; r < 16; ++r) {
        int co = cog * 64 + wv * 16 + r;
        const float* qrow = wsq + (size_t)co * CIN;
        float acc = 0.f;
        for (int k = lane; k < CIN; k += 64) acc += qrow[k] * s2[k];
        for (int off = 32; off; off >>= 1) acc += __shfl_down(acc, off, 64);
        if (lane == 0) dcoef[b * COUT + co] = rsqrtf(acc + 1e-8f);
    }
}

// ------- fused upsample x2 (upfirdn [1,3,3,1]/8) * styles -> channels-last bf16 -------
// xs2[b][row(66)][col(66)][ci(512)].  Block per (oh, b); vectorized 16B stores via
// padded transpose tile.
__global__ __launch_bounds__(256) void upmod3_kernel(
        const float* __restrict__ x,
        const float* __restrict__ styles,
        __hip_bfloat16* __restrict__ xs2) {
    __shared__ __hip_bfloat16 xin[2][128][32];   // rows m0,m1 for a 128-ci chunk
    __shared__ __align__(16) __hip_bfloat16 tt[66][136]; // [ow][ci] transpose tile
    const int oh = blockIdx.x;
    const int b  = blockIdx.y;
    const int tid = threadIdx.x;
    const int lane = tid & 63;
    const int wid = tid >> 6;

    int m0, m1; float a0, a1;
    if (oh & 1) { m0 = (oh - 3) >> 1; a0 = 0.125f; m1 = (oh - 1) >> 1; a1 = 0.375f; }
    else        { m0 = (oh >> 1) - 1; a0 = 0.375f; m1 = (oh >> 1);     a1 = 0.125f; }
    const bool v0 = (m0 >= 0) & (m0 < HIN);
    const bool v1 = (m1 >= 0) & (m1 < HIN);

    // column-tap coefficients for ow = lane, and for tail ow (64,65)
    int p0, p1, t0, t1; float w0c, w1c, u0c, u1c;
    {
        int ow = lane;
        if (ow & 1) { p0 = (ow - 3) >> 1; w0c = 0.125f; p1 = (ow - 1) >> 1; w1c = 0.375f; }
        else        { p0 = (ow >> 1) - 1; w0c = 0.375f; p1 = (ow >> 1);     w1c = 0.125f; }
        if (p0 < 0 || p0 >= HIN) { p0 = 0; w0c = 0.f; }
        if (p1 < 0 || p1 >= HIN) { p1 = 0; w1c = 0.f; }
        int owt = 64 + (tid & 1);
        if (owt & 1) { t0 = (owt - 3) >> 1; u0c = 0.125f; t1 = (owt - 1) >> 1; u1c = 0.375f; }
        else         { t0 = (owt >> 1) - 1; u0c = 0.375f; t1 = (owt >> 1);     u1c = 0.125f; }
        if (t0 < 0 || t0 >= HIN) { t0 = 0; u0c = 0.f; }
        if (t1 < 0 || t1 >= HIN) { t1 = 0; u1c = 0.f; }
    }
    const int ow_t = 64 + (tid & 1);
    const int ci_t = tid >> 1;

    for (int ch = 0; ch < 4; ++ch) {
        const int ci0c = ch * 128;
        // ---- stage rows m0,m1 for 128 ci (float4 loads -> bf16 LDS) ----
#pragma unroll
        for (int j = 0; j < 8; ++j) {
            int e = tid + 256 * j;            // 0..2047
            int sel = e >> 10;
            int ci = (e >> 3) & 127;
            int f4 = e & 7;
            int m = sel ? m1 : m0;
            bool vv = sel ? v1 : v0;
            float4 xv = make_float4(0.f, 0.f, 0.f, 0.f);
            if (vv)
                xv = *(const float4*)(x + (((size_t)(b * CIN + ci0c + ci)) * HIN + m) * HIN + f4 * 4);
            __hip_bfloat16* d = &xin[sel][ci][f4 * 4];
            d[0] = __float2bfloat16(xv.x);
            d[1] = __float2bfloat16(xv.y);
            d[2] = __float2bfloat16(xv.z);
            d[3] = __float2bfloat16(xv.w);
        }
        __syncthreads();
        // ---- compute: lane = ow (0..63), wave covers 32 ci ----
#pragma unroll 4
        for (int k = 0; k < 32; ++k) {
            int ci = wid * 32 + k;
            float s = styles[b * CIN + ci0c + ci] * 4.0f;
            float r0 = __bfloat162float(xin[0][ci][p0]) * w0c +
                       __bfloat162float(xin[0][ci][p1]) * w1c;
            float r1 = __bfloat162float(xin[1][ci][p0]) * w0c +
                       __bfloat162float(xin[1][ci][p1]) * w1c;
            tt[lane][ci] = __float2bfloat16((a0 * r0 + a1 * r1) * s);
        }
        // tail ows 64,65: 256 threads cover 128ci x 2ow
        {
            float s = styles[b * CIN + ci0c + ci_t] * 4.0f;
            float r0 = __bfloat162float(xin[0][ci_t][t0]) * u0c +
                       __bfloat162float(xin[0][ci_t][t1]) * u1c;
            float r1 = __bfloat162float(xin[1][ci_t][t0]) * u0c +
                       __bfloat162float(xin[1][ci_t][t1]) * u1c;
            tt[ow_t][ci_t] = __float2bfloat16((a0 * r0 + a1 * r1) * s);
        }
        __syncthreads();
        // ---- copy out: 16B per lane, ci-contiguous ----
#pragma unroll
        for (int j = 0; j < 5; ++j) {
            int e = tid + 256 * j;            // 66*16 = 1056 slots
            if (e < 1056) {
                int ow = e >> 4, c8 = e & 15;
                ushort8 v = *(const ushort8*)&tt[ow][c8 * 8];
                *(ushort8*)(xs2 + (((size_t)b * HUP + oh) * HUP + ow) * CIN + ci0c + c8 * 8) = v;
            }
        }
        __syncthreads();
    }
}

// ---------------- implicit-GEMM conv via MFMA bf16 16x16x32 ----------------
// block: 4 waves; block tile M=512 px (8 image rows), N=64 cout; K-chunk = 32 ci.
// wave tile: M=128 (8 i-frags) x N=64 (4 j-frags) -> per tap 8 A + 4 B reads, 32 MFMA.
// LDS A: [r(10)][ci_hi(4)][col(66)][ci_lo(8)] bf16 = 42240 B (padded to 43008 = 42 slices)
// LDS B: [t(9)][ci_hi(4)][n(64)][ci_lo(8)]  bf16 = 36864 B (36 slices)
#define A_SLICES 42
#define A_BYTES  43008
#define TOT_SLICES 78
#define CONV_LDS (A_BYTES + 36864)   // 79872 B -> 2 blocks/CU of 160 KiB

__global__ __launch_bounds__(256, 2) void conv_mfma(
        const __hip_bfloat16* __restrict__ xs2,
        const __hip_bfloat16* __restrict__ wb,
        const float* __restrict__ dcoef,
        const float* __restrict__ bias,
        const float* __restrict__ noise,
        const float* __restrict__ nstr,
        float* __restrict__ out)
{
    extern __shared__ __align__(16) char smem[];
    const int tid = threadIdx.x;
    const int lane = tid & 63;
    const int wid = tid >> 6;
    const int li = lane & 15;
    const int q = lane >> 4;
    const int mt = blockIdx.x;        // 0..7 -> 8 image rows each
    const int n0 = blockIdx.y * 64;   // cout base
    const int b  = blockIdx.z;
    const int y0 = mt * 8;

    // ---- staging descriptors: 78 slices of 64 x 16B, interleaved over 4 waves ----
    const char* ga[20];
    int lofs[20];
#pragma unroll
    for (int k = 0; k < 20; ++k) {
        int sl = wid + 4 * k;
        lofs[k] = sl * 1024;
        if (sl < A_SLICES) {
            int slot = sl * 64 + lane;
            if (slot > 2639) slot = 2639;        // clamp tail into A pad region
            int col = slot % 66;
            int rem = slot / 66;
            int chi = rem & 3;
            int r = rem >> 2;
            long elem = ((long)(b * HUP + y0 + r) * HUP + col) * CIN + chi * 8;
            ga[k] = (const char*)xs2 + elem * 2;
        } else if (sl < TOT_SLICES) {
            int sb = sl - A_SLICES;              // 0..35: t = sb>>2, chi = sb&3
            long elem = ((long)sb * COUT + n0 + lane) * 8;
            ga[k] = (const char*)wb + elem * 2;
        } else {
            ga[k] = nullptr;
        }
    }

    float4v acc[8][4];
#pragma unroll
    for (int i = 0; i < 8; ++i)
#pragma unroll
        for (int j = 0; j < 4; ++j) acc[i][j] = (float4v)0.f;

#pragma unroll 1
    for (int cc = 0; cc < 16; ++cc) {
#pragma unroll
        for (int k = 0; k < 20; ++k) {
            if (ga[k]) {
                __builtin_amdgcn_global_load_lds(
                    (const __attribute__((address_space(1))) char*)ga[k],
                    (__attribute__((address_space(3))) char*)(smem + lofs[k]),
                    16, 0, 0);
                ga[k] += (lofs[k] < A_BYTES) ? 64 : 294912;
            }
        }
        __syncthreads();

#pragma unroll
        for (int t = 0; t < 9; ++t) {
            const int kh = t / 3, kw = t - kh * 3;
            short8 bf[4];
#pragma unroll
            for (int j = 0; j < 4; ++j)
                bf[j] = *(const short8*)(smem + A_BYTES +
                        (((t * 4 + q) * 64) + j * 16 + li) * 16);
#pragma unroll
            for (int i = 0; i < 8; ++i) {
                short8 af = *(const short8*)(smem +
                        ((((2 * wid + (i >> 2) + kh) * 4 + q) * 66) +
                         ((i & 3) * 16 + li + kw)) * 16);
#pragma unroll
                for (int j = 0; j < 4; ++j)
                    acc[i][j] = __builtin_amdgcn_mfma_f32_16x16x32_bf16(
                        af, bf[j], acc[i][j], 0, 0, 0);
            }
        }
        __syncthreads();
    }

    // ---- epilogue: *dcoef + noise + bias -> lrelu*gain ----
    const float ns = nstr[0];
    float dc[4], bs[4];
#pragma unroll
    for (int j = 0; j < 4; ++j) {
        int cout = n0 + j * 16 + li;
        dc[j] = dcoef[b * COUT + cout];
        bs[j] = bias[cout];
    }
#pragma unroll
    for (int i = 0; i < 8; ++i) {
        const int row = y0 + 2 * wid + (i >> 2);
        const int colb = (i & 3) * 16 + q * 4;
        float4v nz = *(const float4v*)(noise + row * RES + colb);
#pragma unroll
        for (int j = 0; j < 4; ++j) {
            int cout = n0 + j * 16 + li;
            float4v a = acc[i][j];
            float4v r;
            r.x = a.x * dc[j] + nz.x * ns + bs[j];
            r.y = a.y * dc[j] + nz.y * ns + bs[j];
            r.z = a.z * dc[j] + nz.z * ns + bs[j];
            r.w = a.w * dc[j] + nz.w * ns + bs[j];
            r.x = (r.x > 0.f ? r.x : LRELU * r.x) * ACT_GAIN;
            r.y = (r.y > 0.f ? r.y : LRELU * r.y) * ACT_GAIN;
            r.z = (r.z > 0.f ? r.z : LRELU * r.z) * ACT_GAIN;
            r.w = (r.w > 0.f ? r.w : LRELU * r.w) * ACT_GAIN;
            *(float4v*)(out + (((size_t)b * COUT + cout) * RES + row) * RES + colb) = r;
        }
    }
}

extern "C" void kernel_launch(void* const* d_in, const int* in_sizes, int n_in,
                              void* d_out, int out_size, void* d_ws, size_t ws_size,
                              hipStream_t stream) {
    (void)in_sizes; (void)n_in; (void)out_size; (void)ws_size;
    const float* x     = (const float*)d_in[0];
    const float* w     = (const float*)d_in[1];
    const float* aw    = (const float*)d_in[2];
    const float* ab    = (const float*)d_in[3];
    const float* wt    = (const float*)d_in[4];
    const float* bias  = (const float*)d_in[5];
    const float* noise = (const float*)d_in[6];
    const float* nstr  = (const float*)d_in[7];
    float* out = (float*)d_out;

    char* ws = (char*)d_ws;
    float* styles = (float*)ws;                                   // 32 KB
    float* dcoef  = (float*)(ws + 32768);                         // 32 KB
    float* wsq    = (float*)(ws + 65536);                         // 1 MB
    __hip_bfloat16* wb  = (__hip_bfloat16*)(ws + 65536 + 1048576);          // 4.72 MB
    __hip_bfloat16* xs2 = (__hip_bfloat16*)(ws + 65536 + 1048576 + 4718592); // 71.4 MB

    styles2_kernel<<<dim3(NB, 8), dim3(256), 0, stream>>>(w, aw, ab, styles);
    prep_weights<<<dim3(1024), dim3(256), 0, stream>>>(wt, wsq, wb);
    dcoef2_kernel<<<dim3(NB, 8), dim3(256), 0, stream>>>(styles, wsq, dcoef);
    upmod3_kernel<<<dim3(HUP, NB), dim3(256), 0, stream>>>(x, styles, xs2);
    conv_mfma<<<dim3(8, 8, NB), dim3(256), CONV_LDS, stream>>>(
        xs2, wb, dcoef, bias, noise, nstr, out);
}